// Round 15
// baseline (252.738 us; speedup 1.0000x reference)
//
#include <hip/hip_runtime.h>

#define NN 100000
#define NE 1600000
// IN_CH = HID = 64, OUT_CH = 16

// ---- bucketed CSR build geometry ----
#define BSHIFT 9
#define BWIDTH 512
#define NBUCK 196
#define SLOTS 12288
#define CHUNK 4096                               // edges per B1 block
#define B1_BLOCKS ((NE + CHUNK - 1) / CHUNK)     // 391
#define GEMM_BLOCKS ((NN + 63) / 64)             // 1563
#define AGG_CAP 1024

typedef float    v2f __attribute__((ext_vector_type(2)));
typedef unsigned v2u __attribute__((ext_vector_type(2)));
typedef short    bf16x8 __attribute__((ext_vector_type(8)));
typedef float    f32x4  __attribute__((ext_vector_type(4)));

// ---- bf16 helpers (RNE pack, exact unpack) ----
__device__ __forceinline__ float u2f(unsigned u) {
    union { unsigned u; float f; } v; v.u = u; return v.f;
}
__device__ __forceinline__ unsigned f2u(float f) {
    union { float f; unsigned u; } v; v.f = f; return v.u;
}
__device__ __forceinline__ unsigned f2bf(float f) {   // bf16 in low 16, RNE
    unsigned u = f2u(f);
    return (u + 0x7FFFu + ((u >> 16) & 1u)) >> 16;
}
__device__ __forceinline__ v2f unpk(unsigned x) {
    v2u w; w[0] = x << 16; w[1] = x & 0xFFFF0000u;
    union { v2u u; v2f f; } c; c.u = w; return c.f;
}
// wave-level inclusive scan (64 lanes)
__device__ __forceinline__ int wave_incl_scan(int v, int lane) {
    #pragma unroll
    for (int off = 1; off < 64; off <<= 1) {
        int u = __shfl_up(v, off);
        if (lane >= off) v += u;
    }
    return v;
}

// ---------------------------------------------------------------------------
// Detect int64 vs int32 edge_index; also zeroes bcnt.
__global__ void detect_mode_kernel(const int* ei32, int* flag, int* bcnt) {
    __shared__ int any_nonzero;
    if (threadIdx.x == 0) any_nonzero = 0;
    if (threadIdx.x < NBUCK) bcnt[threadIdx.x] = 0;
    __syncthreads();
    int idx = 1 + 2 * threadIdx.x;
    if (ei32[idx] != 0) atomicOr(&any_nonzero, 1);
    __syncthreads();
    if (threadIdx.x == 0) flag[0] = (any_nonzero == 0) ? 1 : 0;  // 1 => int64
}

__device__ __forceinline__ void load_edge(const void* ei, int is64, int e,
                                          int& s, int& d) {
    if (is64) {
        const long long* p = (const long long*)ei;
        s = (int)p[e];
        d = (int)p[NE + e];
    } else {
        const int* p = (const int*)ei;
        s = p[e];
        d = p[NE + e];
    }
}

// ---------------------------------------------------------------------------
// MFMA GEMM body. Output t goes to the CHANNEL-SPLIT table:
//   T = 4 sub-tables, sub-table q (=c>>4) holds channels q*16..q*16+15 as
//   32 B rows: short index q*(NN+1)*16 + node*16 + (c&15).
// Output r (bias folded) stays row-major bf16 [node][64].
// Waves 0,1 own c 0..63 (t-half); waves 2,3 own c 64..127 (r-half).
template<int BF16IN>
__device__ __forceinline__ void gemm_mfma_body(
    char* smem, const void* __restrict__ featv,
    const float* __restrict__ Wl, const float* __restrict__ Wr,
    const float* __restrict__ bias,
    unsigned* __restrict__ outt, unsigned* __restrict__ outr,
    int tile, int t)
{
    unsigned short* Als = (unsigned short*)smem;            // [64][72] bf16
    unsigned short* Bls = (unsigned short*)(smem + 9216);   // [128][72] bf16
    const int lane = t & 63, w = t >> 6;
    const int m0 = tile * 64;
    const float*    featf = (const float*)featv;
    const unsigned* featu = (const unsigned*)featv;

    #pragma unroll
    for (int rep = 0; rep < 2; ++rep) {
        int task = t + 256 * rep;
        int row = task >> 3, s = task & 7;
        int gn = m0 + row;
        uint4 u;
        if (BF16IN) {
            u = (gn < NN) ? *(const uint4*)(featu + (size_t)gn * 32 + 4 * s)
                          : make_uint4(0u, 0u, 0u, 0u);
        } else {
            if (gn < NN) {
                float4 v0 = *(const float4*)(featf + (size_t)gn * 64 + 8 * s);
                float4 v1 = *(const float4*)(featf + (size_t)gn * 64 + 8 * s + 4);
                u.x = f2bf(v0.x) | (f2bf(v0.y) << 16);
                u.y = f2bf(v0.z) | (f2bf(v0.w) << 16);
                u.z = f2bf(v1.x) | (f2bf(v1.y) << 16);
                u.w = f2bf(v1.z) | (f2bf(v1.w) << 16);
            } else u = make_uint4(0u, 0u, 0u, 0u);
        }
        *(uint4*)(Als + row * 72 + 8 * s) = u;
    }
    #pragma unroll
    for (int rep = 0; rep < 4; ++rep) {
        int task = t + 256 * rep;
        int c = task >> 3, s = task & 7;
        const float* Wsrc = (c < 64) ? (Wl + (size_t)c * 64)
                                     : (Wr + (size_t)(c - 64) * 64);
        float4 v0 = *(const float4*)(Wsrc + 8 * s);
        float4 v1 = *(const float4*)(Wsrc + 8 * s + 4);
        uint4 u;
        u.x = f2bf(v0.x) | (f2bf(v0.y) << 16);
        u.y = f2bf(v0.z) | (f2bf(v0.w) << 16);
        u.z = f2bf(v1.x) | (f2bf(v1.y) << 16);
        u.w = f2bf(v1.z) | (f2bf(v1.w) << 16);
        *(uint4*)(Bls + c * 72 + 8 * s) = u;
    }
    __syncthreads();

    const int r = lane & 15, g = lane >> 4;
    const int cw0 = 32 * w;

    bf16x8 bf[2][2];
    #pragma unroll
    for (int ct = 0; ct < 2; ++ct)
        #pragma unroll
        for (int ks = 0; ks < 2; ++ks) {
            int c = cw0 + 16 * ct + r;
            bf[ct][ks] = *(const bf16x8*)(Bls + c * 72 + (ks * 4 + g) * 8);
        }

    f32x4 acc[4][2];
    #pragma unroll
    for (int nt = 0; nt < 4; ++nt)
        #pragma unroll
        for (int ct = 0; ct < 2; ++ct)
            acc[nt][ct] = (f32x4){0.f, 0.f, 0.f, 0.f};

    #pragma unroll
    for (int nt = 0; nt < 4; ++nt) {
        bf16x8 af[2];
        #pragma unroll
        for (int ks = 0; ks < 2; ++ks) {
            int rr = nt * 16 + r;
            af[ks] = *(const bf16x8*)(Als + rr * 72 + (ks * 4 + g) * 8);
        }
        #pragma unroll
        for (int ct = 0; ct < 2; ++ct)
            #pragma unroll
            for (int ks = 0; ks < 2; ++ks)
                acc[nt][ct] = __builtin_amdgcn_mfma_f32_16x16x32_bf16(
                    af[ks], bf[ct][ks], acc[nt][ct], 0, 0, 0);
    }

    unsigned short* Tb = (unsigned short*)outt;
    unsigned short* Rb = (unsigned short*)outr;
    if (cw0 < 64) {
        // t-half: channel-split sub-tables, 16-short rows
        #pragma unroll
        for (int ct = 0; ct < 2; ++ct) {
            int c = cw0 + 16 * ct + r;
            int q = c >> 4;
            unsigned short* dst = Tb + (size_t)q * (NN + 1) * 16 + (c & 15);
            #pragma unroll
            for (int nt = 0; nt < 4; ++nt)
                #pragma unroll
                for (int i = 0; i < 4; ++i) {
                    int row = m0 + nt * 16 + g * 4 + i;
                    if (row < NN)
                        dst[(size_t)row * 16] = (unsigned short)f2bf(acc[nt][ct][i]);
                }
        }
    } else {
        // r-half: row-major 64-short rows, bias folded
        #pragma unroll
        for (int ct = 0; ct < 2; ++ct) {
            int c = cw0 + 16 * ct + r;
            float badd = bias[c - 64];
            unsigned short* dst = Rb + (c - 64);
            #pragma unroll
            for (int nt = 0; nt < 4; ++nt)
                #pragma unroll
                for (int i = 0; i < 4; ++i) {
                    int row = m0 + nt * 16 + g * 4 + i;
                    if (row < NN)
                        dst[(size_t)row * 64] = (unsigned short)f2bf(acc[nt][ct][i] + badd);
                }
        }
    }
}

// ---------------------------------------------------------------------------
// FUSED: blocks [0, B1_BLOCKS) bucket edges; blocks [B1_BLOCKS, ..) run the
// layer-1 MFMA GEMM. First gemm block also zeroes the 4 sub-table zero rows.
__global__ __launch_bounds__(256) void b1_gemm1_kernel(
    const void* ei, const int* flag,
    int* __restrict__ bcnt, int* __restrict__ bpk,
    const float* __restrict__ x,
    const float* __restrict__ W1l, const float* __restrict__ W1r,
    const float* __restrict__ b1,
    unsigned* __restrict__ T, unsigned* __restrict__ R)
{
    __shared__ __align__(16) char smem[27648];
    const int t = threadIdx.x;

    if (blockIdx.x >= B1_BLOCKS) {
        if (blockIdx.x == B1_BLOCKS && t < 32) {
            int q = t >> 3, i = t & 7;     // zero row NN of each sub-table
            T[(size_t)q * (NN + 1) * 8 + (size_t)NN * 8 + i] = 0u;
        }
        gemm_mfma_body<0>(smem, x, W1l, W1r, b1, T, R, blockIdx.x - B1_BLOCKS, t);
        return;
    }

    // ---------------- B1 part ----------------
    int* stage = (int*)smem;                                     // 16384
    unsigned char* sbuck = (unsigned char*)(smem + 16384);       // 4096
    int* hist  = (int*)(smem + 20480);                           // 784
    int* scanb = (int*)(smem + 21264);
    int* gbase = (int*)(smem + 22048);
    int* lofs  = (int*)(smem + 22832);
    int* wsum  = (int*)(smem + 23616);                           // 16

    const int is64 = *flag;
    const int e0 = blockIdx.x * CHUNK;
    const int nE = min(CHUNK, NE - e0);
    const int lane = t & 63, wvi = t >> 6;

    for (int i = t; i < NBUCK; i += 256) { hist[i] = 0; lofs[i] = 0; }
    __syncthreads();

    int sr[16], dr[16];
    #pragma unroll
    for (int rr = 0; rr < 16; ++rr) {
        int e = e0 + t + 256 * rr;
        if (e < NE) load_edge(ei, is64, e, sr[rr], dr[rr]);
        else dr[rr] = -1;
    }
    #pragma unroll
    for (int rr = 0; rr < 16; ++rr)
        if (dr[rr] >= 0) atomicAdd(&hist[dr[rr] >> BSHIFT], 1);
    __syncthreads();

    int v = (t < NBUCK) ? hist[t] : 0;
    int s = wave_incl_scan(v, lane);
    if (lane == 63) wsum[wvi] = s;
    __syncthreads();
    int add = 0;
    #pragma unroll
    for (int k = 0; k < 3; ++k) if (wvi > k) add += wsum[k];
    s += add;
    if (t < NBUCK) {
        scanb[t] = s - v;
        gbase[t] = atomicAdd(&bcnt[t], v);
    }
    __syncthreads();

    #pragma unroll
    for (int rr = 0; rr < 16; ++rr) {
        if (dr[rr] >= 0) {
            int b = dr[rr] >> BSHIFT;
            int p = scanb[b] + atomicAdd(&lofs[b], 1);
            stage[p] = (sr[rr] << BSHIFT) | (dr[rr] & (BWIDTH - 1));
            sbuck[p] = (unsigned char)b;
        }
    }
    __syncthreads();

    for (int i = t; i < nE; i += 256) {
        int b = sbuck[i];
        int off = gbase[b] + (i - scanb[b]);
        if (off < SLOTS) bpk[(size_t)b * SLOTS + off] = stage[i];
    }
}

// ---------------------------------------------------------------------------
// B3 (512 threads): packed bucket -> rowptr + colb (byte offsets into a
// 32 B-row sub-table: src*32), with in-block bucket prefix; shfl scans.
__global__ __launch_bounds__(512) void bucket_to_csr_kernel(
    const int* __restrict__ bcnt, const int* __restrict__ bpk,
    int* __restrict__ rowptr, int* __restrict__ colb)
{
    __shared__ int ldeg[512], lptr[512], lcnt[512], sc[512], wsum[8];
    const int t = threadIdx.x, b = blockIdx.x;
    const int lane = t & 63, wvi = t >> 6;

    int v = (t < NBUCK) ? bcnt[t] : 0;
    int s = wave_incl_scan(v, lane);
    if (lane == 63) wsum[wvi] = s;
    __syncthreads();
    int add = 0;
    #pragma unroll
    for (int k = 0; k < 7; ++k) if (wvi > k) add += wsum[k];
    s += add;
    sc[t] = s;
    __syncthreads();
    const int base = (b == 0) ? 0 : sc[b - 1];
    if (b == 0 && t == 0) rowptr[NN] = NE;
    __syncthreads();

    ldeg[t] = 0; lcnt[t] = 0;
    __syncthreads();

    const int n0 = b << BSHIFT;
    const int cnt = min(bcnt[b], SLOTS);
    const int* src = bpk + (size_t)b * SLOTS;
    for (int i = t; i < cnt; i += 512)
        atomicAdd(&ldeg[src[i] & (BWIDTH - 1)], 1);
    __syncthreads();

    int a = ldeg[t];
    int s2 = wave_incl_scan(a, lane);
    if (lane == 63) wsum[wvi] = s2;
    __syncthreads();
    int add2 = 0;
    #pragma unroll
    for (int k = 0; k < 7; ++k) if (wvi > k) add2 += wsum[k];
    s2 += add2;
    lptr[t] = s2 - a;
    __syncthreads();

    int gn = n0 + t;
    if (gn < NN) rowptr[gn] = base + lptr[t];

    for (int i = t; i < cnt; i += 512) {
        int p = src[i];
        int li = p & (BWIDTH - 1);
        int pos = lptr[li] + atomicAdd(&lcnt[li], 1);
        colb[base + pos] = (p >> BSHIFT) << 5;   // src * 32 B (sub-table row)
    }
}

// ---------------------------------------------------------------------------
// Standalone layer-2 MFMA GEMM (bf16 input features; in-place safe per-tile).
__global__ __launch_bounds__(256) void gemm2_kernel(
    const unsigned* __restrict__ feat,
    const float* __restrict__ Wl, const float* __restrict__ Wr,
    const float* __restrict__ bias,
    unsigned* __restrict__ outt, unsigned* __restrict__ outr)
{
    __shared__ __align__(16) char smem[27648];
    gemm_mfma_body<1>(smem, feat, Wl, Wr, bias, outt, outr, blockIdx.x, threadIdx.x);
}

// ---------------------------------------------------------------------------
// Gather-mean + epilogue: rh(bf16) <- relu(mean + rh), in 4 channel-quarter
// passes. Pass q gathers ONLY from sub-table q (3.2 MB -> L2-resident).
// Block = 8 nodes; col list staged in LDS once, reused by all 4 passes.
// Lane = half(1b node) x slot(4b, 16 edges in flight) x cq(1b, 8 channels).
__global__ void aggregate_relu_kernel(const int* __restrict__ rowptr,
                                      const int* __restrict__ colb,
                                      const unsigned* __restrict__ tt,  // 4 sub-tables
                                      unsigned* rh) {                   // NN x 32
    __shared__ int lcol[AGG_CAP];
    const int t = threadIdx.x;
    const int n0 = blockIdx.x * 8;
    const int lane = t & 63;
    const int w = t >> 6;
    const int half = lane >> 5;
    const int slot = (lane >> 1) & 15;
    const int cq   = lane & 1;
    const int node = n0 + 2 * w + half;

    const int cbeg  = rowptr[n0];
    const int cendB = rowptr[min(n0 + 8, NN)];
    const int total = cendB - cbeg;
    const bool fast = (total <= AGG_CAP);
    if (fast) {
        for (int i = t; i < total; i += 256) lcol[i] = colb[cbeg + i];
    }
    __syncthreads();

    if (node >= NN) return;
    const int beg = rowptr[node], end = rowptr[node + 1];
    const int deg = end - beg;
    int niter = (deg + 15) >> 4;
    niter = max(niter, __shfl_xor(niter, 32));   // wave-uniform

    const char* tb = (const char*)tt;
    const int zoff = NN * 32;                    // zero row within sub-table
    const float inv = 1.0f / fmaxf((float)deg, 1.0f);

    #pragma unroll
    for (int q = 0; q < 4; ++q) {
        const size_t qbase = (size_t)q * (NN + 1) * 32;
        v2f a0 = {0.f, 0.f}, a1 = {0.f, 0.f}, a2 = {0.f, 0.f}, a3 = {0.f, 0.f};
        int jj = beg + slot;
        for (int it = 0; it < niter; ++it, jj += 16) {
            int o;
            if (fast) { int jc = min(jj, end - 1) - cbeg; o = lcol[jc]; }
            else      { int jc = min(jj, end - 1);        o = colb[jc]; }
            o = (jj < end) ? o : zoff;
            uint4 u = *(const uint4*)(tb + qbase + (size_t)(unsigned)o + 16 * cq);
            a0 += unpk(u.x); a1 += unpk(u.y); a2 += unpk(u.z); a3 += unpk(u.w);
        }
        // reduce over slot bits (lane bits 1..4)
        #pragma unroll
        for (int m = 2; m <= 16; m <<= 1) {
            a0[0] += __shfl_xor(a0[0], m); a0[1] += __shfl_xor(a0[1], m);
            a1[0] += __shfl_xor(a1[0], m); a1[1] += __shfl_xor(a1[1], m);
            a2[0] += __shfl_xor(a2[0], m); a2[1] += __shfl_xor(a2[1], m);
            a3[0] += __shfl_xor(a3[0], m); a3[1] += __shfl_xor(a3[1], m);
        }
        if (slot == 0) {
            unsigned* p = rh + (size_t)node * 32 + q * 8 + cq * 4;
            uint4 rr = *(const uint4*)p;
            v2f q0 = unpk(rr.x), q1 = unpk(rr.y), q2 = unpk(rr.z), q3 = unpk(rr.w);
            float h0 = fmaxf(fmaf(a0[0], inv, q0[0]), 0.0f);
            float h1 = fmaxf(fmaf(a0[1], inv, q0[1]), 0.0f);
            float h2 = fmaxf(fmaf(a1[0], inv, q1[0]), 0.0f);
            float h3 = fmaxf(fmaf(a1[1], inv, q1[1]), 0.0f);
            float h4 = fmaxf(fmaf(a2[0], inv, q2[0]), 0.0f);
            float h5 = fmaxf(fmaf(a2[1], inv, q2[1]), 0.0f);
            float h6 = fmaxf(fmaf(a3[0], inv, q3[0]), 0.0f);
            float h7 = fmaxf(fmaf(a3[1], inv, q3[1]), 0.0f);
            uint4 wv4;
            wv4.x = f2bf(h0) | (f2bf(h1) << 16);
            wv4.y = f2bf(h2) | (f2bf(h3) << 16);
            wv4.z = f2bf(h4) | (f2bf(h5) << 16);
            wv4.w = f2bf(h6) | (f2bf(h7) << 16);
            *(uint4*)p = wv4;
        }
    }
}

// ---------------------------------------------------------------------------
// Head GEMM: out = h(bf16) @ Wlin.T + blin.
__global__ __launch_bounds__(256) void head_kernel(
    const unsigned* __restrict__ hu,      // NN x 32 bf16x2
    const float* __restrict__ Wlin,
    const float* __restrict__ blin,
    float* __restrict__ out)
{
    __shared__ float As[64][132];
    __shared__ float Bs[64][18];
    const int t = threadIdx.x;

    {
        int c = t & 15, j = t >> 4;
        float4 v = *(const float4*)(Wlin + (size_t)c * 64 + 4 * j);
        Bs[4 * j + 0][c] = v.x; Bs[4 * j + 1][c] = v.y;
        Bs[4 * j + 2][c] = v.z; Bs[4 * j + 3][c] = v.w;
    }
    const int m0 = blockIdx.x * 128;
    {
        int kq = t & 7;
        int nb = t >> 3;
        for (int rep = 0; rep < 4; ++rep) {
            int n = nb + 32 * rep;
            int gn = m0 + n;
            uint4 u = (gn < NN) ? *(const uint4*)(hu + (size_t)gn * 32 + 4 * kq)
                                : make_uint4(0u, 0u, 0u, 0u);
            int kk = 8 * kq;
            As[kk + 0][n] = u2f(u.x << 16); As[kk + 1][n] = u2f(u.x & 0xFFFF0000u);
            As[kk + 2][n] = u2f(u.y << 16); As[kk + 3][n] = u2f(u.y & 0xFFFF0000u);
            As[kk + 4][n] = u2f(u.z << 16); As[kk + 5][n] = u2f(u.z & 0xFFFF0000u);
            As[kk + 6][n] = u2f(u.w << 16); As[kk + 7][n] = u2f(u.w & 0xFFFF0000u);
        }
    }
    __syncthreads();

    const int tn = t & 31;
    const int tc = t >> 5;
    const int c0 = 2 * tc;
    float acc[4][2];
    #pragma unroll
    for (int i = 0; i < 4; ++i) { acc[i][0] = blin[c0]; acc[i][1] = blin[c0 + 1]; }

    #pragma unroll 16
    for (int k = 0; k < 64; ++k) {
        float4 a = *(const float4*)&As[k][4 * tn];
        float b0 = Bs[k][c0], b1 = Bs[k][c0 + 1];
        float av[4] = {a.x, a.y, a.z, a.w};
        #pragma unroll
        for (int i = 0; i < 4; ++i) {
            acc[i][0] = fmaf(av[i], b0, acc[i][0]);
            acc[i][1] = fmaf(av[i], b1, acc[i][1]);
        }
    }
    #pragma unroll
    for (int i = 0; i < 4; ++i) {
        int gn = m0 + 4 * tn + i;
        if (gn < NN)
            *(float2*)(out + (size_t)gn * 16 + c0) = make_float2(acc[i][0], acc[i][1]);
    }
}

// ---------------------------------------------------------------------------
extern "C" void kernel_launch(void* const* d_in, const int* in_sizes, int n_in,
                              void* d_out, int out_size, void* d_ws, size_t ws_size,
                              hipStream_t stream) {
    const float* x    = (const float*)d_in[0];
    const void*  ei   = d_in[1];
    const float* W1l  = (const float*)d_in[2];
    const float* b1   = (const float*)d_in[3];
    const float* W1r  = (const float*)d_in[4];
    const float* W2l  = (const float*)d_in[5];
    const float* b2   = (const float*)d_in[6];
    const float* W2r  = (const float*)d_in[7];
    const float* Wlin = (const float*)d_in[8];
    const float* blin = (const float*)d_in[9];
    float* out = (float*)d_out;

    char* w = (char*)d_ws;
    int*      flag   = (int*)w;                                   // @ 0
    int*      bcnt   = (int*)(w + (size_t)4 * 1024);              // @ 4K
    int*      rowptr = (int*)(w + (size_t)1024 * 1024);           // @ 1M  (400 KB+4)
    int*      colb   = (int*)(w + (size_t)2 * 1024 * 1024);       // @ 2M  (6.4 MB)
    int*      bpk    = (int*)(w + (size_t)10 * 1024 * 1024);      // @ 10M (9.6 MB packed)
    unsigned* T      = (unsigned*)(w + (size_t)30 * 1024 * 1024); // @ 30M (12.8 MB + 4 zero rows)
    unsigned* R      = (unsigned*)(w + (size_t)43 * 1024 * 1024); // @ 43M (12.8 MB bf16 r/h)

    detect_mode_kernel<<<1, 256, 0, stream>>>((const int*)ei, flag, bcnt);

    // ---- fused: B1 (blocks 0..390) + layer-1 MFMA GEMM (blocks 391..) ----
    b1_gemm1_kernel<<<B1_BLOCKS + GEMM_BLOCKS, 256, 0, stream>>>(
        ei, flag, bcnt, bpk, x, W1l, W1r, b1, T, R);

    bucket_to_csr_kernel<<<NBUCK, 512, 0, stream>>>(bcnt, bpk, rowptr, colb);

    const int aggBlocks = (NN + 7) / 8;        // 12500 (8 nodes per block)
    const int headBlocks = (NN + 127) / 128;

    aggregate_relu_kernel<<<aggBlocks, 256, 0, stream>>>(rowptr, colb, T, R); // h1 in R

    gemm2_kernel<<<GEMM_BLOCKS, 256, 0, stream>>>(R, W2l, W2r, b2, T, R);
    aggregate_relu_kernel<<<aggBlocks, 256, 0, stream>>>(rowptr, colb, T, R); // h2 in R

    head_kernel<<<headBlocks, 256, 0, stream>>>(R, Wlin, blin, out);
}

// Round 16
// 168.461 us; speedup vs baseline: 1.5003x; 1.5003x over previous
//
#include <hip/hip_runtime.h>

#define NN 100000
#define NE 1600000
// IN_CH = HID = 64, OUT_CH = 16

// ---- bucketed CSR build geometry ----
#define BSHIFT 9
#define BWIDTH 512
#define NBUCK 196
#define SLOTS 12288
#define CHUNK 4096                               // edges per B1 block
#define B1_BLOCKS ((NE + CHUNK - 1) / CHUNK)     // 391
#define GEMM_BLOCKS ((NN + 63) / 64)             // 1563
#define AGG_CAP 1024

typedef float    v2f __attribute__((ext_vector_type(2)));
typedef unsigned v2u __attribute__((ext_vector_type(2)));
typedef short    bf16x8 __attribute__((ext_vector_type(8)));
typedef float    f32x4  __attribute__((ext_vector_type(4)));

// ---- bf16 helpers (RNE pack, exact unpack) ----
__device__ __forceinline__ float u2f(unsigned u) {
    union { unsigned u; float f; } v; v.u = u; return v.f;
}
__device__ __forceinline__ unsigned f2u(float f) {
    union { float f; unsigned u; } v; v.f = f; return v.u;
}
__device__ __forceinline__ unsigned f2bf(float f) {   // bf16 in low 16, RNE
    unsigned u = f2u(f);
    return (u + 0x7FFFu + ((u >> 16) & 1u)) >> 16;
}
__device__ __forceinline__ v2f unpk(unsigned x) {
    v2u w; w[0] = x << 16; w[1] = x & 0xFFFF0000u;
    union { v2u u; v2f f; } c; c.u = w; return c.f;
}
// wave-level inclusive scan (64 lanes)
__device__ __forceinline__ int wave_incl_scan(int v, int lane) {
    #pragma unroll
    for (int off = 1; off < 64; off <<= 1) {
        int u = __shfl_up(v, off);
        if (lane >= off) v += u;
    }
    return v;
}

// ---------------------------------------------------------------------------
// Detect int64 vs int32 edge_index; also zeroes bcnt.
__global__ void detect_mode_kernel(const int* ei32, int* flag, int* bcnt) {
    __shared__ int any_nonzero;
    if (threadIdx.x == 0) any_nonzero = 0;
    if (threadIdx.x < NBUCK) bcnt[threadIdx.x] = 0;
    __syncthreads();
    int idx = 1 + 2 * threadIdx.x;
    if (ei32[idx] != 0) atomicOr(&any_nonzero, 1);
    __syncthreads();
    if (threadIdx.x == 0) flag[0] = (any_nonzero == 0) ? 1 : 0;  // 1 => int64
}

__device__ __forceinline__ void load_edge(const void* ei, int is64, int e,
                                          int& s, int& d) {
    if (is64) {
        const long long* p = (const long long*)ei;
        s = (int)p[e];
        d = (int)p[NE + e];
    } else {
        const int* p = (const int*)ei;
        s = p[e];
        d = p[NE + e];
    }
}

// ---------------------------------------------------------------------------
// MFMA GEMM body: t(bf16) = feat @ Wl.T ; r(bf16, +bias) = feat @ Wr.T.
// Block = 256 thr = 4 waves; tile 64 nodes x 128 ch; wave w owns 32 channels.
template<int BF16IN>
__device__ __forceinline__ void gemm_mfma_body(
    char* smem, const void* __restrict__ featv,
    const float* __restrict__ Wl, const float* __restrict__ Wr,
    const float* __restrict__ bias,
    unsigned* __restrict__ outt, unsigned* __restrict__ outr,
    int tile, int t)
{
    unsigned short* Als = (unsigned short*)smem;            // [64][72] bf16
    unsigned short* Bls = (unsigned short*)(smem + 9216);   // [128][72] bf16
    const int lane = t & 63, w = t >> 6;
    const int m0 = tile * 64;
    const float*    featf = (const float*)featv;
    const unsigned* featu = (const unsigned*)featv;

    #pragma unroll
    for (int rep = 0; rep < 2; ++rep) {
        int task = t + 256 * rep;
        int row = task >> 3, s = task & 7;
        int gn = m0 + row;
        uint4 u;
        if (BF16IN) {
            u = (gn < NN) ? *(const uint4*)(featu + (size_t)gn * 32 + 4 * s)
                          : make_uint4(0u, 0u, 0u, 0u);
        } else {
            if (gn < NN) {
                float4 v0 = *(const float4*)(featf + (size_t)gn * 64 + 8 * s);
                float4 v1 = *(const float4*)(featf + (size_t)gn * 64 + 8 * s + 4);
                u.x = f2bf(v0.x) | (f2bf(v0.y) << 16);
                u.y = f2bf(v0.z) | (f2bf(v0.w) << 16);
                u.z = f2bf(v1.x) | (f2bf(v1.y) << 16);
                u.w = f2bf(v1.z) | (f2bf(v1.w) << 16);
            } else u = make_uint4(0u, 0u, 0u, 0u);
        }
        *(uint4*)(Als + row * 72 + 8 * s) = u;
    }
    #pragma unroll
    for (int rep = 0; rep < 4; ++rep) {
        int task = t + 256 * rep;
        int c = task >> 3, s = task & 7;
        const float* Wsrc = (c < 64) ? (Wl + (size_t)c * 64)
                                     : (Wr + (size_t)(c - 64) * 64);
        float4 v0 = *(const float4*)(Wsrc + 8 * s);
        float4 v1 = *(const float4*)(Wsrc + 8 * s + 4);
        uint4 u;
        u.x = f2bf(v0.x) | (f2bf(v0.y) << 16);
        u.y = f2bf(v0.z) | (f2bf(v0.w) << 16);
        u.z = f2bf(v1.x) | (f2bf(v1.y) << 16);
        u.w = f2bf(v1.z) | (f2bf(v1.w) << 16);
        *(uint4*)(Bls + c * 72 + 8 * s) = u;
    }
    __syncthreads();

    const int r = lane & 15, g = lane >> 4;
    const int cw0 = 32 * w;

    bf16x8 bf[2][2];
    #pragma unroll
    for (int ct = 0; ct < 2; ++ct)
        #pragma unroll
        for (int ks = 0; ks < 2; ++ks) {
            int c = cw0 + 16 * ct + r;
            bf[ct][ks] = *(const bf16x8*)(Bls + c * 72 + (ks * 4 + g) * 8);
        }

    f32x4 acc[4][2];
    #pragma unroll
    for (int nt = 0; nt < 4; ++nt)
        #pragma unroll
        for (int ct = 0; ct < 2; ++ct)
            acc[nt][ct] = (f32x4){0.f, 0.f, 0.f, 0.f};

    #pragma unroll
    for (int nt = 0; nt < 4; ++nt) {
        bf16x8 af[2];
        #pragma unroll
        for (int ks = 0; ks < 2; ++ks) {
            int rr = nt * 16 + r;
            af[ks] = *(const bf16x8*)(Als + rr * 72 + (ks * 4 + g) * 8);
        }
        #pragma unroll
        for (int ct = 0; ct < 2; ++ct)
            #pragma unroll
            for (int ks = 0; ks < 2; ++ks)
                acc[nt][ct] = __builtin_amdgcn_mfma_f32_16x16x32_bf16(
                    af[ks], bf[ct][ks], acc[nt][ct], 0, 0, 0);
    }

    unsigned short* Tb = (unsigned short*)outt;
    unsigned short* Rb = (unsigned short*)outr;
    #pragma unroll
    for (int ct = 0; ct < 2; ++ct) {
        int c = cw0 + 16 * ct + r;
        float badd = (c >= 64) ? bias[c - 64] : 0.f;
        unsigned short* dst = (c < 64) ? (Tb + c) : (Rb + (c - 64));
        #pragma unroll
        for (int nt = 0; nt < 4; ++nt)
            #pragma unroll
            for (int i = 0; i < 4; ++i) {
                int row = m0 + nt * 16 + g * 4 + i;
                if (row < NN)
                    dst[(size_t)row * 64] = (unsigned short)f2bf(acc[nt][ct][i] + badd);
            }
    }
}

// ---------------------------------------------------------------------------
// FUSED: blocks [0, B1_BLOCKS) bucket edges (packed 4B entries, CHUNK=4096,
// shfl scans); blocks [B1_BLOCKS, ..) run the layer-1 MFMA GEMM.
__global__ __launch_bounds__(256) void b1_gemm1_kernel(
    const void* ei, const int* flag,
    int* __restrict__ bcnt, int* __restrict__ bpk,
    const float* __restrict__ x,
    const float* __restrict__ W1l, const float* __restrict__ W1r,
    const float* __restrict__ b1,
    unsigned* __restrict__ T, unsigned* __restrict__ R)
{
    __shared__ __align__(16) char smem[27648];
    const int t = threadIdx.x;

    if (blockIdx.x >= B1_BLOCKS) {
        if (blockIdx.x == B1_BLOCKS && t < 32) T[(size_t)NN * 32 + t] = 0u; // zero row
        gemm_mfma_body<0>(smem, x, W1l, W1r, b1, T, R, blockIdx.x - B1_BLOCKS, t);
        return;
    }

    // ---------------- B1 part ----------------
    int* stage = (int*)smem;                                     // 16384
    unsigned char* sbuck = (unsigned char*)(smem + 16384);       // 4096
    int* hist  = (int*)(smem + 20480);                           // 784
    int* scanb = (int*)(smem + 21264);
    int* gbase = (int*)(smem + 22048);
    int* lofs  = (int*)(smem + 22832);
    int* wsum  = (int*)(smem + 23616);                           // 16

    const int is64 = *flag;
    const int e0 = blockIdx.x * CHUNK;
    const int nE = min(CHUNK, NE - e0);
    const int lane = t & 63, wvi = t >> 6;

    for (int i = t; i < NBUCK; i += 256) { hist[i] = 0; lofs[i] = 0; }
    __syncthreads();

    int sr[16], dr[16];
    #pragma unroll
    for (int rr = 0; rr < 16; ++rr) {
        int e = e0 + t + 256 * rr;
        if (e < NE) load_edge(ei, is64, e, sr[rr], dr[rr]);
        else dr[rr] = -1;
    }
    #pragma unroll
    for (int rr = 0; rr < 16; ++rr)
        if (dr[rr] >= 0) atomicAdd(&hist[dr[rr] >> BSHIFT], 1);
    __syncthreads();

    int v = (t < NBUCK) ? hist[t] : 0;
    int s = wave_incl_scan(v, lane);
    if (lane == 63) wsum[wvi] = s;
    __syncthreads();
    int add = 0;
    #pragma unroll
    for (int k = 0; k < 3; ++k) if (wvi > k) add += wsum[k];
    s += add;
    if (t < NBUCK) {
        scanb[t] = s - v;
        gbase[t] = atomicAdd(&bcnt[t], v);
    }
    __syncthreads();

    #pragma unroll
    for (int rr = 0; rr < 16; ++rr) {
        if (dr[rr] >= 0) {
            int b = dr[rr] >> BSHIFT;
            int p = scanb[b] + atomicAdd(&lofs[b], 1);
            stage[p] = (sr[rr] << BSHIFT) | (dr[rr] & (BWIDTH - 1));
            sbuck[p] = (unsigned char)b;
        }
    }
    __syncthreads();

    for (int i = t; i < nE; i += 256) {
        int b = sbuck[i];
        int off = gbase[b] + (i - scanb[b]);
        if (off < SLOTS) bpk[(size_t)b * SLOTS + off] = stage[i];
    }
}

// ---------------------------------------------------------------------------
// B3 (512 threads): packed bucket -> rowptr + colb (byte offsets), with
// in-block bucket prefix; all scans via wave shfl.
__global__ __launch_bounds__(512) void bucket_to_csr_kernel(
    const int* __restrict__ bcnt, const int* __restrict__ bpk,
    int* __restrict__ rowptr, int* __restrict__ colb)
{
    __shared__ int ldeg[512], lptr[512], lcnt[512], sc[512], wsum[8];
    const int t = threadIdx.x, b = blockIdx.x;
    const int lane = t & 63, wvi = t >> 6;

    int v = (t < NBUCK) ? bcnt[t] : 0;
    int s = wave_incl_scan(v, lane);
    if (lane == 63) wsum[wvi] = s;
    __syncthreads();
    int add = 0;
    #pragma unroll
    for (int k = 0; k < 7; ++k) if (wvi > k) add += wsum[k];
    s += add;
    sc[t] = s;
    __syncthreads();
    const int base = (b == 0) ? 0 : sc[b - 1];
    if (b == 0 && t == 0) rowptr[NN] = NE;
    __syncthreads();

    ldeg[t] = 0; lcnt[t] = 0;
    __syncthreads();

    const int n0 = b << BSHIFT;
    const int cnt = min(bcnt[b], SLOTS);
    const int* src = bpk + (size_t)b * SLOTS;
    for (int i = t; i < cnt; i += 512)
        atomicAdd(&ldeg[src[i] & (BWIDTH - 1)], 1);
    __syncthreads();

    int a = ldeg[t];
    int s2 = wave_incl_scan(a, lane);
    if (lane == 63) wsum[wvi] = s2;
    __syncthreads();
    int add2 = 0;
    #pragma unroll
    for (int k = 0; k < 7; ++k) if (wvi > k) add2 += wsum[k];
    s2 += add2;
    lptr[t] = s2 - a;
    __syncthreads();

    int gn = n0 + t;
    if (gn < NN) rowptr[gn] = base + lptr[t];

    for (int i = t; i < cnt; i += 512) {
        int p = src[i];
        int li = p & (BWIDTH - 1);
        int pos = lptr[li] + atomicAdd(&lcnt[li], 1);
        colb[base + pos] = (p >> BSHIFT) << 7;   // src byte offset into table
    }
}

// ---------------------------------------------------------------------------
// Standalone layer-2 MFMA GEMM (bf16 input features; in-place safe per-tile).
__global__ __launch_bounds__(256) void gemm2_kernel(
    const unsigned* __restrict__ feat,
    const float* __restrict__ Wl, const float* __restrict__ Wr,
    const float* __restrict__ bias,
    unsigned* __restrict__ outt, unsigned* __restrict__ outr)
{
    __shared__ __align__(16) char smem[27648];
    gemm_mfma_body<1>(smem, feat, Wl, Wr, bias, outt, outr, blockIdx.x, threadIdx.x);
}

// ---------------------------------------------------------------------------
// Gather-mean (bf16 table) + epilogue. Block = 8 nodes; col range staged in
// LDS (contiguous). FINAL=0: rh <- relu(mean + rh) (bf16, global).
// FINAL=1: h2 kept in LDS only; fused head computes out = h2 @ Wlin.T + blin.
// h2 passes through the SAME bf16 RNE rounding as the stored path, so the
// numerics match the unfused version exactly.
#define AGG_STEP(O0, O1, O2, O3)                                              \
    {                                                                         \
        int o0 = O0, o1 = O1, o2 = O2, o3 = O3;                               \
        o0 = (jj      < end) ? o0 : zoff;                                     \
        o1 = (jj + 4  < end) ? o1 : zoff;                                     \
        o2 = (jj + 8  < end) ? o2 : zoff;                                     \
        o3 = (jj + 12 < end) ? o3 : zoff;                                     \
        uint4 u0 = *(const uint4*)(tb + (size_t)(unsigned)o0 + 16 * c8);      \
        uint4 u1 = *(const uint4*)(tb + (size_t)(unsigned)o1 + 16 * c8);      \
        uint4 u2 = *(const uint4*)(tb + (size_t)(unsigned)o2 + 16 * c8);      \
        uint4 u3 = *(const uint4*)(tb + (size_t)(unsigned)o3 + 16 * c8);      \
        a0 += unpk(u0.x); a1 += unpk(u0.y); a2 += unpk(u0.z); a3 += unpk(u0.w);\
        b0 += unpk(u1.x); b1 += unpk(u1.y); b2 += unpk(u1.z); b3 += unpk(u1.w);\
        a0 += unpk(u2.x); a1 += unpk(u2.y); a2 += unpk(u2.z); a3 += unpk(u2.w);\
        b0 += unpk(u3.x); b1 += unpk(u3.y); b2 += unpk(u3.z); b3 += unpk(u3.w);\
    }

template<int FINAL>
__global__ void aggregate_relu_kernel(const int* __restrict__ rowptr,
                                      const int* __restrict__ colb,
                                      const unsigned* __restrict__ tt,  // (NN+1) x 32
                                      unsigned* rh,                     // NN x 32
                                      const float* __restrict__ Wlin,
                                      const float* __restrict__ blin,
                                      float* __restrict__ out) {
    __shared__ int lcol[AGG_CAP];
    __shared__ float wls[1024];                   // Wlin 16x64 (FINAL only)
    __shared__ unsigned short hbuf[8][72];        // h2 rows (FINAL only)
    const int t = threadIdx.x;
    const int n0 = blockIdx.x * 8;
    const int lane = t & 63;
    const int w = t >> 6;
    const int half = lane >> 5;
    const int slot = (lane >> 3) & 3;
    const int c8   = lane & 7;
    const int node = n0 + 2 * w + half;           // NN % 8 == 0 -> always < NN

    const int cbeg  = rowptr[n0];
    const int cendB = rowptr[min(n0 + 8, NN)];
    const int total = cendB - cbeg;
    const bool fast = (total <= AGG_CAP);
    if (fast) {
        for (int i = t; i < total; i += 256) lcol[i] = colb[cbeg + i];
    }
    if (FINAL) {
        for (int i = t; i < 1024; i += 256) wls[i] = Wlin[i];
    }
    __syncthreads();

    const int beg = rowptr[node], end = rowptr[node + 1];
    const int deg = end - beg;
    int niter = (deg + 3) >> 2;
    niter = max(niter, __shfl_xor(niter, 32));   // wave-uniform

    const char* tb = (const char*)tt;
    const int zoff = NN * 128;                   // zero row (byte offset)
    v2f a0 = {0.f, 0.f}, a1 = {0.f, 0.f}, a2 = {0.f, 0.f}, a3 = {0.f, 0.f};
    v2f b0 = {0.f, 0.f}, b1 = {0.f, 0.f}, b2 = {0.f, 0.f}, b3 = {0.f, 0.f};

    int jj = beg + slot;
    int it = 0;
    if (fast) {
        for (; it + 4 <= niter; it += 4, jj += 16) {
            int jc0 = min(jj,      end - 1) - cbeg;
            int jc1 = min(jj + 4,  end - 1) - cbeg;
            int jc2 = min(jj + 8,  end - 1) - cbeg;
            int jc3 = min(jj + 12, end - 1) - cbeg;
            AGG_STEP(lcol[jc0], lcol[jc1], lcol[jc2], lcol[jc3])
        }
        for (; it < niter; ++it, jj += 4) {
            int jc0 = min(jj, end - 1) - cbeg;
            int o0 = lcol[jc0];
            o0 = (jj < end) ? o0 : zoff;
            uint4 u0 = *(const uint4*)(tb + (size_t)(unsigned)o0 + 16 * c8);
            a0 += unpk(u0.x); a1 += unpk(u0.y); a2 += unpk(u0.z); a3 += unpk(u0.w);
        }
    } else {
        for (; it + 4 <= niter; it += 4, jj += 16) {
            int jc0 = min(jj,      end - 1);
            int jc1 = min(jj + 4,  end - 1);
            int jc2 = min(jj + 8,  end - 1);
            int jc3 = min(jj + 12, end - 1);
            AGG_STEP(colb[jc0], colb[jc1], colb[jc2], colb[jc3])
        }
        for (; it < niter; ++it, jj += 4) {
            int jc0 = min(jj, end - 1);
            int o0 = colb[jc0];
            o0 = (jj < end) ? o0 : zoff;
            uint4 u0 = *(const uint4*)(tb + (size_t)(unsigned)o0 + 16 * c8);
            a0 += unpk(u0.x); a1 += unpk(u0.y); a2 += unpk(u0.z); a3 += unpk(u0.w);
        }
    }
    a0 += b0; a1 += b1; a2 += b2; a3 += b3;

    a0[0] += __shfl_xor(a0[0], 8);  a0[1] += __shfl_xor(a0[1], 8);
    a1[0] += __shfl_xor(a1[0], 8);  a1[1] += __shfl_xor(a1[1], 8);
    a2[0] += __shfl_xor(a2[0], 8);  a2[1] += __shfl_xor(a2[1], 8);
    a3[0] += __shfl_xor(a3[0], 8);  a3[1] += __shfl_xor(a3[1], 8);
    a0[0] += __shfl_xor(a0[0], 16); a0[1] += __shfl_xor(a0[1], 16);
    a1[0] += __shfl_xor(a1[0], 16); a1[1] += __shfl_xor(a1[1], 16);
    a2[0] += __shfl_xor(a2[0], 16); a2[1] += __shfl_xor(a2[1], 16);
    a3[0] += __shfl_xor(a3[0], 16); a3[1] += __shfl_xor(a3[1], 16);

    if (slot == 0) {
        float inv = 1.0f / fmaxf((float)deg, 1.0f);
        unsigned* p = rh + (size_t)node * 32 + 4 * c8;
        uint4 rr = *(const uint4*)p;
        v2f q0 = unpk(rr.x), q1 = unpk(rr.y), q2 = unpk(rr.z), q3 = unpk(rr.w);
        float h0 = fmaxf(fmaf(a0[0], inv, q0[0]), 0.0f);
        float h1 = fmaxf(fmaf(a0[1], inv, q0[1]), 0.0f);
        float h2 = fmaxf(fmaf(a1[0], inv, q1[0]), 0.0f);
        float h3 = fmaxf(fmaf(a1[1], inv, q1[1]), 0.0f);
        float h4 = fmaxf(fmaf(a2[0], inv, q2[0]), 0.0f);
        float h5 = fmaxf(fmaf(a2[1], inv, q2[1]), 0.0f);
        float h6 = fmaxf(fmaf(a3[0], inv, q3[0]), 0.0f);
        float h7 = fmaxf(fmaf(a3[1], inv, q3[1]), 0.0f);
        uint4 wv4;
        wv4.x = f2bf(h0) | (f2bf(h1) << 16);
        wv4.y = f2bf(h2) | (f2bf(h3) << 16);
        wv4.z = f2bf(h4) | (f2bf(h5) << 16);
        wv4.w = f2bf(h6) | (f2bf(h7) << 16);
        if (FINAL) {
            *(uint4*)&hbuf[2 * w + half][8 * c8] = wv4;   // LDS only
        } else {
            *(uint4*)p = wv4;                              // h1 to global
        }
    }

    if (FINAL) {
        __syncthreads();
        // head: 128 threads, thread = (node i = t>>4, out ch cc = t&15)
        if (t < 128) {
            int i = t >> 4, cc = t & 15;
            int gnode = n0 + i;
            const unsigned* hrow = (const unsigned*)hbuf[i];
            float acc = blin[cc];
            #pragma unroll
            for (int k2 = 0; k2 < 32; ++k2) {
                v2f hv = unpk(hrow[k2]);
                acc = fmaf(hv[0], wls[cc * 64 + 2 * k2], acc);
                acc = fmaf(hv[1], wls[cc * 64 + 2 * k2 + 1], acc);
            }
            if (gnode < NN)
                out[(size_t)gnode * 16 + cc] = acc;
        }
    }
}

// ---------------------------------------------------------------------------
extern "C" void kernel_launch(void* const* d_in, const int* in_sizes, int n_in,
                              void* d_out, int out_size, void* d_ws, size_t ws_size,
                              hipStream_t stream) {
    const float* x    = (const float*)d_in[0];
    const void*  ei   = d_in[1];
    const float* W1l  = (const float*)d_in[2];
    const float* b1   = (const float*)d_in[3];
    const float* W1r  = (const float*)d_in[4];
    const float* W2l  = (const float*)d_in[5];
    const float* b2   = (const float*)d_in[6];
    const float* W2r  = (const float*)d_in[7];
    const float* Wlin = (const float*)d_in[8];
    const float* blin = (const float*)d_in[9];
    float* out = (float*)d_out;

    char* w = (char*)d_ws;
    int*      flag   = (int*)w;                                   // @ 0
    int*      bcnt   = (int*)(w + (size_t)4 * 1024);              // @ 4K
    int*      rowptr = (int*)(w + (size_t)1024 * 1024);           // @ 1M  (400 KB+4)
    int*      colb   = (int*)(w + (size_t)2 * 1024 * 1024);       // @ 2M  (6.4 MB)
    int*      bpk    = (int*)(w + (size_t)10 * 1024 * 1024);      // @ 10M (9.6 MB packed)
    unsigned* T      = (unsigned*)(w + (size_t)30 * 1024 * 1024); // @ 30M (12.8 MB + zero row)
    unsigned* R      = (unsigned*)(w + (size_t)43 * 1024 * 1024); // @ 43M (12.8 MB bf16 r/h)

    detect_mode_kernel<<<1, 256, 0, stream>>>((const int*)ei, flag, bcnt);

    // ---- fused: B1 (blocks 0..390) + layer-1 MFMA GEMM (blocks 391..) ----
    b1_gemm1_kernel<<<B1_BLOCKS + GEMM_BLOCKS, 256, 0, stream>>>(
        ei, flag, bcnt, bpk, x, W1l, W1r, b1, T, R);

    bucket_to_csr_kernel<<<NBUCK, 512, 0, stream>>>(bcnt, bpk, rowptr, colb);

    const int aggBlocks = (NN + 7) / 8;        // 12500 (8 nodes per block)

    aggregate_relu_kernel<0><<<aggBlocks, 256, 0, stream>>>(
        rowptr, colb, T, R, nullptr, nullptr, nullptr);           // h1 in R

    gemm2_kernel<<<GEMM_BLOCKS, 256, 0, stream>>>(R, W2l, W2r, b2, T, R);

    // final aggregate + fused head (h2 never hits global)
    aggregate_relu_kernel<1><<<aggBlocks, 256, 0, stream>>>(
        rowptr, colb, T, R, Wlin, blin, out);
}

// Round 17
// 145.284 us; speedup vs baseline: 1.7396x; 1.1595x over previous
//
#include <hip/hip_runtime.h>

#define NN 100000
#define NE 1600000
// IN_CH = HID = 64, OUT_CH = 16

// ---- bucketed CSR build geometry ----
#define BSHIFT 9
#define BWIDTH 512
#define NBUCK 196
#define SLOTS 12288
#define CHUNK 4096                               // edges per B1 block
#define B1_BLOCKS ((NE + CHUNK - 1) / CHUNK)     // 391
#define GEMM_BLOCKS ((NN + 63) / 64)             // 1563
#define AGG_CAP 1024

typedef float    v2f __attribute__((ext_vector_type(2)));
typedef unsigned v2u __attribute__((ext_vector_type(2)));
typedef short    bf16x8 __attribute__((ext_vector_type(8)));
typedef float    f32x4  __attribute__((ext_vector_type(4)));

// ---- bf16 helpers (RNE pack, exact unpack) ----
__device__ __forceinline__ float u2f(unsigned u) {
    union { unsigned u; float f; } v; v.u = u; return v.f;
}
__device__ __forceinline__ unsigned f2u(float f) {
    union { float f; unsigned u; } v; v.f = f; return v.u;
}
__device__ __forceinline__ unsigned f2bf(float f) {   // bf16 in low 16, RNE
    unsigned u = f2u(f);
    return (u + 0x7FFFu + ((u >> 16) & 1u)) >> 16;
}
__device__ __forceinline__ v2f unpk(unsigned x) {
    v2u w; w[0] = x << 16; w[1] = x & 0xFFFF0000u;
    union { v2u u; v2f f; } c; c.u = w; return c.f;
}
// wave-level inclusive scan (64 lanes)
__device__ __forceinline__ int wave_incl_scan(int v, int lane) {
    #pragma unroll
    for (int off = 1; off < 64; off <<= 1) {
        int u = __shfl_up(v, off);
        if (lane >= off) v += u;
    }
    return v;
}

// ---------------------------------------------------------------------------
// Detect int64 vs int32 edge_index; also zeroes bcnt.
__global__ void detect_mode_kernel(const int* ei32, int* flag, int* bcnt) {
    __shared__ int any_nonzero;
    if (threadIdx.x == 0) any_nonzero = 0;
    if (threadIdx.x < NBUCK) bcnt[threadIdx.x] = 0;
    __syncthreads();
    int idx = 1 + 2 * threadIdx.x;
    if (ei32[idx] != 0) atomicOr(&any_nonzero, 1);
    __syncthreads();
    if (threadIdx.x == 0) flag[0] = (any_nonzero == 0) ? 1 : 0;  // 1 => int64
}

__device__ __forceinline__ void load_edge(const void* ei, int is64, int e,
                                          int& s, int& d) {
    if (is64) {
        const long long* p = (const long long*)ei;
        s = (int)p[e];
        d = (int)p[NE + e];
    } else {
        const int* p = (const int*)ei;
        s = p[e];
        d = p[NE + e];
    }
}

// ---------------------------------------------------------------------------
// MFMA GEMM body: t(bf16) = feat @ Wl.T ; r(bf16, +bias) = feat @ Wr.T.
// Block = 256 thr = 4 waves; tile 64 nodes x 128 ch; wave w owns 32 channels.
template<int BF16IN>
__device__ __forceinline__ void gemm_mfma_body(
    char* smem, const void* __restrict__ featv,
    const float* __restrict__ Wl, const float* __restrict__ Wr,
    const float* __restrict__ bias,
    unsigned* __restrict__ outt, unsigned* __restrict__ outr,
    int tile, int t)
{
    unsigned short* Als = (unsigned short*)smem;            // [64][72] bf16
    unsigned short* Bls = (unsigned short*)(smem + 9216);   // [128][72] bf16
    const int lane = t & 63, w = t >> 6;
    const int m0 = tile * 64;
    const float*    featf = (const float*)featv;
    const unsigned* featu = (const unsigned*)featv;

    #pragma unroll
    for (int rep = 0; rep < 2; ++rep) {
        int task = t + 256 * rep;
        int row = task >> 3, s = task & 7;
        int gn = m0 + row;
        uint4 u;
        if (BF16IN) {
            u = (gn < NN) ? *(const uint4*)(featu + (size_t)gn * 32 + 4 * s)
                          : make_uint4(0u, 0u, 0u, 0u);
        } else {
            if (gn < NN) {
                float4 v0 = *(const float4*)(featf + (size_t)gn * 64 + 8 * s);
                float4 v1 = *(const float4*)(featf + (size_t)gn * 64 + 8 * s + 4);
                u.x = f2bf(v0.x) | (f2bf(v0.y) << 16);
                u.y = f2bf(v0.z) | (f2bf(v0.w) << 16);
                u.z = f2bf(v1.x) | (f2bf(v1.y) << 16);
                u.w = f2bf(v1.z) | (f2bf(v1.w) << 16);
            } else u = make_uint4(0u, 0u, 0u, 0u);
        }
        *(uint4*)(Als + row * 72 + 8 * s) = u;
    }
    #pragma unroll
    for (int rep = 0; rep < 4; ++rep) {
        int task = t + 256 * rep;
        int c = task >> 3, s = task & 7;
        const float* Wsrc = (c < 64) ? (Wl + (size_t)c * 64)
                                     : (Wr + (size_t)(c - 64) * 64);
        float4 v0 = *(const float4*)(Wsrc + 8 * s);
        float4 v1 = *(const float4*)(Wsrc + 8 * s + 4);
        uint4 u;
        u.x = f2bf(v0.x) | (f2bf(v0.y) << 16);
        u.y = f2bf(v0.z) | (f2bf(v0.w) << 16);
        u.z = f2bf(v1.x) | (f2bf(v1.y) << 16);
        u.w = f2bf(v1.z) | (f2bf(v1.w) << 16);
        *(uint4*)(Bls + c * 72 + 8 * s) = u;
    }
    __syncthreads();

    const int r = lane & 15, g = lane >> 4;
    const int cw0 = 32 * w;

    bf16x8 bf[2][2];
    #pragma unroll
    for (int ct = 0; ct < 2; ++ct)
        #pragma unroll
        for (int ks = 0; ks < 2; ++ks) {
            int c = cw0 + 16 * ct + r;
            bf[ct][ks] = *(const bf16x8*)(Bls + c * 72 + (ks * 4 + g) * 8);
        }

    f32x4 acc[4][2];
    #pragma unroll
    for (int nt = 0; nt < 4; ++nt)
        #pragma unroll
        for (int ct = 0; ct < 2; ++ct)
            acc[nt][ct] = (f32x4){0.f, 0.f, 0.f, 0.f};

    #pragma unroll
    for (int nt = 0; nt < 4; ++nt) {
        bf16x8 af[2];
        #pragma unroll
        for (int ks = 0; ks < 2; ++ks) {
            int rr = nt * 16 + r;
            af[ks] = *(const bf16x8*)(Als + rr * 72 + (ks * 4 + g) * 8);
        }
        #pragma unroll
        for (int ct = 0; ct < 2; ++ct)
            #pragma unroll
            for (int ks = 0; ks < 2; ++ks)
                acc[nt][ct] = __builtin_amdgcn_mfma_f32_16x16x32_bf16(
                    af[ks], bf[ct][ks], acc[nt][ct], 0, 0, 0);
    }

    unsigned short* Tb = (unsigned short*)outt;
    unsigned short* Rb = (unsigned short*)outr;
    #pragma unroll
    for (int ct = 0; ct < 2; ++ct) {
        int c = cw0 + 16 * ct + r;
        float badd = (c >= 64) ? bias[c - 64] : 0.f;
        unsigned short* dst = (c < 64) ? (Tb + c) : (Rb + (c - 64));
        #pragma unroll
        for (int nt = 0; nt < 4; ++nt)
            #pragma unroll
            for (int i = 0; i < 4; ++i) {
                int row = m0 + nt * 16 + g * 4 + i;
                if (row < NN)
                    dst[(size_t)row * 64] = (unsigned short)f2bf(acc[nt][ct][i] + badd);
            }
    }
}

// ---------------------------------------------------------------------------
// FUSED: blocks [0, B1_BLOCKS) bucket edges (packed 4B entries, CHUNK=4096,
// shfl scans); blocks [B1_BLOCKS, ..) run the layer-1 MFMA GEMM.
__global__ __launch_bounds__(256) void b1_gemm1_kernel(
    const void* ei, const int* flag,
    int* __restrict__ bcnt, int* __restrict__ bpk,
    const float* __restrict__ x,
    const float* __restrict__ W1l, const float* __restrict__ W1r,
    const float* __restrict__ b1,
    unsigned* __restrict__ T, unsigned* __restrict__ R)
{
    __shared__ __align__(16) char smem[27648];
    const int t = threadIdx.x;

    if (blockIdx.x >= B1_BLOCKS) {
        if (blockIdx.x == B1_BLOCKS && t < 32) T[(size_t)NN * 32 + t] = 0u; // zero row
        gemm_mfma_body<0>(smem, x, W1l, W1r, b1, T, R, blockIdx.x - B1_BLOCKS, t);
        return;
    }

    // ---------------- B1 part ----------------
    int* stage = (int*)smem;                                     // 16384
    unsigned char* sbuck = (unsigned char*)(smem + 16384);       // 4096
    int* hist  = (int*)(smem + 20480);                           // 784
    int* scanb = (int*)(smem + 21264);
    int* gbase = (int*)(smem + 22048);
    int* lofs  = (int*)(smem + 22832);
    int* wsum  = (int*)(smem + 23616);                           // 16

    const int is64 = *flag;
    const int e0 = blockIdx.x * CHUNK;
    const int nE = min(CHUNK, NE - e0);
    const int lane = t & 63, wvi = t >> 6;

    for (int i = t; i < NBUCK; i += 256) { hist[i] = 0; lofs[i] = 0; }
    __syncthreads();

    int sr[16], dr[16];
    #pragma unroll
    for (int rr = 0; rr < 16; ++rr) {
        int e = e0 + t + 256 * rr;
        if (e < NE) load_edge(ei, is64, e, sr[rr], dr[rr]);
        else dr[rr] = -1;
    }
    #pragma unroll
    for (int rr = 0; rr < 16; ++rr)
        if (dr[rr] >= 0) atomicAdd(&hist[dr[rr] >> BSHIFT], 1);
    __syncthreads();

    int v = (t < NBUCK) ? hist[t] : 0;
    int s = wave_incl_scan(v, lane);
    if (lane == 63) wsum[wvi] = s;
    __syncthreads();
    int add = 0;
    #pragma unroll
    for (int k = 0; k < 3; ++k) if (wvi > k) add += wsum[k];
    s += add;
    if (t < NBUCK) {
        scanb[t] = s - v;
        gbase[t] = atomicAdd(&bcnt[t], v);
    }
    __syncthreads();

    #pragma unroll
    for (int rr = 0; rr < 16; ++rr) {
        if (dr[rr] >= 0) {
            int b = dr[rr] >> BSHIFT;
            int p = scanb[b] + atomicAdd(&lofs[b], 1);
            stage[p] = (sr[rr] << BSHIFT) | (dr[rr] & (BWIDTH - 1));
            sbuck[p] = (unsigned char)b;
        }
    }
    __syncthreads();

    for (int i = t; i < nE; i += 256) {
        int b = sbuck[i];
        int off = gbase[b] + (i - scanb[b]);
        if (off < SLOTS) bpk[(size_t)b * SLOTS + off] = stage[i];
    }
}

// ---------------------------------------------------------------------------
// B3 (512 threads): packed bucket -> rowptr + colb (byte offsets), with
// in-block bucket prefix; all scans via wave shfl.
__global__ __launch_bounds__(512) void bucket_to_csr_kernel(
    const int* __restrict__ bcnt, const int* __restrict__ bpk,
    int* __restrict__ rowptr, int* __restrict__ colb)
{
    __shared__ int ldeg[512], lptr[512], lcnt[512], sc[512], wsum[8];
    const int t = threadIdx.x, b = blockIdx.x;
    const int lane = t & 63, wvi = t >> 6;

    int v = (t < NBUCK) ? bcnt[t] : 0;
    int s = wave_incl_scan(v, lane);
    if (lane == 63) wsum[wvi] = s;
    __syncthreads();
    int add = 0;
    #pragma unroll
    for (int k = 0; k < 7; ++k) if (wvi > k) add += wsum[k];
    s += add;
    sc[t] = s;
    __syncthreads();
    const int base = (b == 0) ? 0 : sc[b - 1];
    if (b == 0 && t == 0) rowptr[NN] = NE;
    __syncthreads();

    ldeg[t] = 0; lcnt[t] = 0;
    __syncthreads();

    const int n0 = b << BSHIFT;
    const int cnt = min(bcnt[b], SLOTS);
    const int* src = bpk + (size_t)b * SLOTS;
    for (int i = t; i < cnt; i += 512)
        atomicAdd(&ldeg[src[i] & (BWIDTH - 1)], 1);
    __syncthreads();

    int a = ldeg[t];
    int s2 = wave_incl_scan(a, lane);
    if (lane == 63) wsum[wvi] = s2;
    __syncthreads();
    int add2 = 0;
    #pragma unroll
    for (int k = 0; k < 7; ++k) if (wvi > k) add2 += wsum[k];
    s2 += add2;
    lptr[t] = s2 - a;
    __syncthreads();

    int gn = n0 + t;
    if (gn < NN) rowptr[gn] = base + lptr[t];

    for (int i = t; i < cnt; i += 512) {
        int p = src[i];
        int li = p & (BWIDTH - 1);
        int pos = lptr[li] + atomicAdd(&lcnt[li], 1);
        colb[base + pos] = (p >> BSHIFT) << 7;   // src byte offset into table
    }
}

// ---------------------------------------------------------------------------
// Standalone layer-2 MFMA GEMM (bf16 input features; in-place safe per-tile).
__global__ __launch_bounds__(256) void gemm2_kernel(
    const unsigned* __restrict__ feat,
    const float* __restrict__ Wl, const float* __restrict__ Wr,
    const float* __restrict__ bias,
    unsigned* __restrict__ outt, unsigned* __restrict__ outr)
{
    __shared__ __align__(16) char smem[27648];
    gemm_mfma_body<1>(smem, feat, Wl, Wr, bias, outt, outr, blockIdx.x, threadIdx.x);
}

// ---------------------------------------------------------------------------
// Gather-mean (bf16 table) + epilogue. Block = 8 nodes; col range staged in
// LDS (contiguous). FINAL=0: rh <- relu(mean + rh) (bf16, global).
// FINAL=1: h2 kept in LDS only; fused head computes out = h2 @ Wlin.T + blin.
// wls uses STRIDE 68 (floats): head reads hit banks (4cc+2k)%32 -> 2-way
// broadcast (free), vs stride 64 which was a 16-way conflict (round-16 bug).
#define AGG_STEP(O0, O1, O2, O3)                                              \
    {                                                                         \
        int o0 = O0, o1 = O1, o2 = O2, o3 = O3;                               \
        o0 = (jj      < end) ? o0 : zoff;                                     \
        o1 = (jj + 4  < end) ? o1 : zoff;                                     \
        o2 = (jj + 8  < end) ? o2 : zoff;                                     \
        o3 = (jj + 12 < end) ? o3 : zoff;                                     \
        uint4 u0 = *(const uint4*)(tb + (size_t)(unsigned)o0 + 16 * c8);      \
        uint4 u1 = *(const uint4*)(tb + (size_t)(unsigned)o1 + 16 * c8);      \
        uint4 u2 = *(const uint4*)(tb + (size_t)(unsigned)o2 + 16 * c8);      \
        uint4 u3 = *(const uint4*)(tb + (size_t)(unsigned)o3 + 16 * c8);      \
        a0 += unpk(u0.x); a1 += unpk(u0.y); a2 += unpk(u0.z); a3 += unpk(u0.w);\
        b0 += unpk(u1.x); b1 += unpk(u1.y); b2 += unpk(u1.z); b3 += unpk(u1.w);\
        a0 += unpk(u2.x); a1 += unpk(u2.y); a2 += unpk(u2.z); a3 += unpk(u2.w);\
        b0 += unpk(u3.x); b1 += unpk(u3.y); b2 += unpk(u3.z); b3 += unpk(u3.w);\
    }

template<int FINAL>
__global__ void aggregate_relu_kernel(const int* __restrict__ rowptr,
                                      const int* __restrict__ colb,
                                      const unsigned* __restrict__ tt,  // (NN+1) x 32
                                      unsigned* rh,                     // NN x 32
                                      const float* __restrict__ Wlin,
                                      const float* __restrict__ blin,
                                      float* __restrict__ out) {
    __shared__ int lcol[AGG_CAP];
    __shared__ float wls[16 * 68];                // Wlin, stride 68 (FINAL only)
    __shared__ unsigned short hbuf[8][72];        // h2 rows (FINAL only)
    const int t = threadIdx.x;
    const int n0 = blockIdx.x * 8;
    const int lane = t & 63;
    const int w = t >> 6;
    const int half = lane >> 5;
    const int slot = (lane >> 3) & 3;
    const int c8   = lane & 7;
    const int node = n0 + 2 * w + half;           // NN % 8 == 0 -> always < NN

    const int cbeg  = rowptr[n0];
    const int cendB = rowptr[min(n0 + 8, NN)];
    const int total = cendB - cbeg;
    const bool fast = (total <= AGG_CAP);
    if (fast) {
        for (int i = t; i < total; i += 256) lcol[i] = colb[cbeg + i];
    }
    if (FINAL) {
        for (int i = t; i < 1024; i += 256) {
            int cc = i >> 6, k = i & 63;
            wls[cc * 68 + k] = Wlin[i];
        }
    }
    __syncthreads();

    const int beg = rowptr[node], end = rowptr[node + 1];
    const int deg = end - beg;
    int niter = (deg + 3) >> 2;
    niter = max(niter, __shfl_xor(niter, 32));   // wave-uniform

    const char* tb = (const char*)tt;
    const int zoff = NN * 128;                   // zero row (byte offset)
    v2f a0 = {0.f, 0.f}, a1 = {0.f, 0.f}, a2 = {0.f, 0.f}, a3 = {0.f, 0.f};
    v2f b0 = {0.f, 0.f}, b1 = {0.f, 0.f}, b2 = {0.f, 0.f}, b3 = {0.f, 0.f};

    int jj = beg + slot;
    int it = 0;
    if (fast) {
        for (; it + 4 <= niter; it += 4, jj += 16) {
            int jc0 = min(jj,      end - 1) - cbeg;
            int jc1 = min(jj + 4,  end - 1) - cbeg;
            int jc2 = min(jj + 8,  end - 1) - cbeg;
            int jc3 = min(jj + 12, end - 1) - cbeg;
            AGG_STEP(lcol[jc0], lcol[jc1], lcol[jc2], lcol[jc3])
        }
        for (; it < niter; ++it, jj += 4) {
            int jc0 = min(jj, end - 1) - cbeg;
            int o0 = lcol[jc0];
            o0 = (jj < end) ? o0 : zoff;
            uint4 u0 = *(const uint4*)(tb + (size_t)(unsigned)o0 + 16 * c8);
            a0 += unpk(u0.x); a1 += unpk(u0.y); a2 += unpk(u0.z); a3 += unpk(u0.w);
        }
    } else {
        for (; it + 4 <= niter; it += 4, jj += 16) {
            int jc0 = min(jj,      end - 1);
            int jc1 = min(jj + 4,  end - 1);
            int jc2 = min(jj + 8,  end - 1);
            int jc3 = min(jj + 12, end - 1);
            AGG_STEP(colb[jc0], colb[jc1], colb[jc2], colb[jc3])
        }
        for (; it < niter; ++it, jj += 4) {
            int jc0 = min(jj, end - 1);
            int o0 = colb[jc0];
            o0 = (jj < end) ? o0 : zoff;
            uint4 u0 = *(const uint4*)(tb + (size_t)(unsigned)o0 + 16 * c8);
            a0 += unpk(u0.x); a1 += unpk(u0.y); a2 += unpk(u0.z); a3 += unpk(u0.w);
        }
    }
    a0 += b0; a1 += b1; a2 += b2; a3 += b3;

    a0[0] += __shfl_xor(a0[0], 8);  a0[1] += __shfl_xor(a0[1], 8);
    a1[0] += __shfl_xor(a1[0], 8);  a1[1] += __shfl_xor(a1[1], 8);
    a2[0] += __shfl_xor(a2[0], 8);  a2[1] += __shfl_xor(a2[1], 8);
    a3[0] += __shfl_xor(a3[0], 8);  a3[1] += __shfl_xor(a3[1], 8);
    a0[0] += __shfl_xor(a0[0], 16); a0[1] += __shfl_xor(a0[1], 16);
    a1[0] += __shfl_xor(a1[0], 16); a1[1] += __shfl_xor(a1[1], 16);
    a2[0] += __shfl_xor(a2[0], 16); a2[1] += __shfl_xor(a2[1], 16);
    a3[0] += __shfl_xor(a3[0], 16); a3[1] += __shfl_xor(a3[1], 16);

    if (slot == 0) {
        float inv = 1.0f / fmaxf((float)deg, 1.0f);
        unsigned* p = rh + (size_t)node * 32 + 4 * c8;
        uint4 rr = *(const uint4*)p;
        v2f q0 = unpk(rr.x), q1 = unpk(rr.y), q2 = unpk(rr.z), q3 = unpk(rr.w);
        float h0 = fmaxf(fmaf(a0[0], inv, q0[0]), 0.0f);
        float h1 = fmaxf(fmaf(a0[1], inv, q0[1]), 0.0f);
        float h2 = fmaxf(fmaf(a1[0], inv, q1[0]), 0.0f);
        float h3 = fmaxf(fmaf(a1[1], inv, q1[1]), 0.0f);
        float h4 = fmaxf(fmaf(a2[0], inv, q2[0]), 0.0f);
        float h5 = fmaxf(fmaf(a2[1], inv, q2[1]), 0.0f);
        float h6 = fmaxf(fmaf(a3[0], inv, q3[0]), 0.0f);
        float h7 = fmaxf(fmaf(a3[1], inv, q3[1]), 0.0f);
        uint4 wv4;
        wv4.x = f2bf(h0) | (f2bf(h1) << 16);
        wv4.y = f2bf(h2) | (f2bf(h3) << 16);
        wv4.z = f2bf(h4) | (f2bf(h5) << 16);
        wv4.w = f2bf(h6) | (f2bf(h7) << 16);
        if (FINAL) {
            *(uint4*)&hbuf[2 * w + half][8 * c8] = wv4;   // LDS only
        } else {
            *(uint4*)p = wv4;                              // h1 to global
        }
    }

    if (FINAL) {
        __syncthreads();
        // head: 128 threads, thread = (node i = t>>4, out ch cc = t&15)
        if (t < 128) {
            int i = t >> 4, cc = t & 15;
            int gnode = n0 + i;
            const unsigned* hrow = (const unsigned*)hbuf[i];
            float acc = blin[cc];
            #pragma unroll
            for (int k2 = 0; k2 < 32; ++k2) {
                v2f hv = unpk(hrow[k2]);
                acc = fmaf(hv[0], wls[cc * 68 + 2 * k2], acc);
                acc = fmaf(hv[1], wls[cc * 68 + 2 * k2 + 1], acc);
            }
            if (gnode < NN)
                out[(size_t)gnode * 16 + cc] = acc;
        }
    }
}

// ---------------------------------------------------------------------------
extern "C" void kernel_launch(void* const* d_in, const int* in_sizes, int n_in,
                              void* d_out, int out_size, void* d_ws, size_t ws_size,
                              hipStream_t stream) {
    const float* x    = (const float*)d_in[0];
    const void*  ei   = d_in[1];
    const float* W1l  = (const float*)d_in[2];
    const float* b1   = (const float*)d_in[3];
    const float* W1r  = (const float*)d_in[4];
    const float* W2l  = (const float*)d_in[5];
    const float* b2   = (const float*)d_in[6];
    const float* W2r  = (const float*)d_in[7];
    const float* Wlin = (const float*)d_in[8];
    const float* blin = (const float*)d_in[9];
    float* out = (float*)d_out;

    char* w = (char*)d_ws;
    int*      flag   = (int*)w;                                   // @ 0
    int*      bcnt   = (int*)(w + (size_t)4 * 1024);              // @ 4K
    int*      rowptr = (int*)(w + (size_t)1024 * 1024);           // @ 1M  (400 KB+4)
    int*      colb   = (int*)(w + (size_t)2 * 1024 * 1024);       // @ 2M  (6.4 MB)
    int*      bpk    = (int*)(w + (size_t)10 * 1024 * 1024);      // @ 10M (9.6 MB packed)
    unsigned* T      = (unsigned*)(w + (size_t)30 * 1024 * 1024); // @ 30M (12.8 MB + zero row)
    unsigned* R      = (unsigned*)(w + (size_t)43 * 1024 * 1024); // @ 43M (12.8 MB bf16 r/h)

    detect_mode_kernel<<<1, 256, 0, stream>>>((const int*)ei, flag, bcnt);

    // ---- fused: B1 (blocks 0..390) + layer-1 MFMA GEMM (blocks 391..) ----
    b1_gemm1_kernel<<<B1_BLOCKS + GEMM_BLOCKS, 256, 0, stream>>>(
        ei, flag, bcnt, bpk, x, W1l, W1r, b1, T, R);

    bucket_to_csr_kernel<<<NBUCK, 512, 0, stream>>>(bcnt, bpk, rowptr, colb);

    const int aggBlocks = (NN + 7) / 8;        // 12500 (8 nodes per block)

    aggregate_relu_kernel<0><<<aggBlocks, 256, 0, stream>>>(
        rowptr, colb, T, R, nullptr, nullptr, nullptr);           // h1 in R

    gemm2_kernel<<<GEMM_BLOCKS, 256, 0, stream>>>(R, W2l, W2r, b2, T, R);

    // final aggregate + fused head (h2 never hits global)
    aggregate_relu_kernel<1><<<aggBlocks, 256, 0, stream>>>(
        rowptr, colb, T, R, Wlin, blin, out);
}